// Round 4
// baseline (2520.597 us; speedup 1.0000x reference)
//
#include <hip/hip_runtime.h>
#include <float.h>

#define B 16
#define H 256
#define W 256
#define C 64
#define TH 16
#define TW 16
#define NTH (H / TH)          // 16
#define NTW (W / TW)          // 16
#define NTILES (B * NTH * NTW) // 4096
#define HG 4                  // h-groups per block (= waves)
#define HH 4                  // rows per thread
#define GRID 1024             // persistent blocks (4/CU target)

// ---------------------------------------------------------------------------
// k_init: zero the 4096 tile flags + the ticket counter (flags[NTILES]).
// Must run every call: the harness does not re-poison ws between replays.
// ---------------------------------------------------------------------------
__global__ __launch_bounds__(256) void k_init(int* __restrict__ flags)
{
    int i = blockIdx.x * 256 + threadIdx.x;
    for (; i <= NTILES; i += 16 * 256) flags[i] = 0;
}

// ---------------------------------------------------------------------------
// k_corner: persistent ticketed single-pass corner pool.
// Per tile [16h x 16w x 64c] held in registers (thread = (c, 4-row group)):
//   1. load tile (nt loads, read-once)
//   2. publish h-partial (per (w,c) max over 16h) and w-partial (per (h,c)
//      max over 16w) -- DEPENDENCY-FREE -> fence -> release flag
//   3. decoupled lookback: max over published partials of tiles below (h)
//      and to the right (w)
//   4. in-register local suffixes + seeds -> out = hsuf + wsuf (nt stores)
// Deadlock-free: publishes never wait; tickets ordered deps-first.
// ---------------------------------------------------------------------------
__global__ __launch_bounds__(256, 4) void k_corner(const float* __restrict__ in,
                                                   float* __restrict__ out,
                                                   float* __restrict__ hpart,
                                                   float* __restrict__ wpart,
                                                   int* __restrict__ flags,
                                                   int* __restrict__ counter)
{
    __shared__ float exch[HG][TW][C];   // 16 KiB: per-group 4-row h-maxes
    __shared__ int tkt;
    const int tid = threadIdx.x;
    const int c  = tid & 63;            // lane = channel -> 256B coalesced
    const int hg = tid >> 6;            // wave id = row group

    for (;;) {
        __syncthreads();                // protect exch + tkt reuse
        if (tid == 0) tkt = atomicAdd(counter, 1);
        __syncthreads();
        const int ticket = tkt;
        if (ticket >= NTILES) break;

        // ticket -> (b,t,s): batches interleaved, rows bottom-up, cols
        // right-to-left => every lookback target has a SMALLER ticket.
        const int b = ticket & 15;
        const int r = ticket >> 4;          // 0..255
        const int t = 15 - (r >> 4);
        const int s = 15 - (r & 15);
        const int TI = (b * NTH + t) * NTW + s;

        const size_t imgbase =
            ((size_t)(b * H + t * TH + hg * HH) * W + s * TW) * C + c;

        // ---- 1. load tile into registers --------------------------------
        float v[HH][TW];
#pragma unroll
        for (int hh = 0; hh < HH; ++hh) {
            const float* p = in + imgbase + (size_t)hh * (W * C);
#pragma unroll
            for (int w = 0; w < TW; ++w)
                v[hh][w] = __builtin_nontemporal_load(&p[w * C]);
        }

        // ---- 2. publish partials (dependency-free) ----------------------
#pragma unroll
        for (int w = 0; w < TW; ++w)
            exch[hg][w][c] = fmaxf(fmaxf(v[0][w], v[1][w]),
                                   fmaxf(v[2][w], v[3][w]));
        __syncthreads();

        // seed h-run with groups strictly below within the tile
        float run16[TW];
#pragma unroll
        for (int w = 0; w < TW; ++w) {
            float m = -FLT_MAX;
            for (int gg = hg + 1; gg < HG; ++gg)
                m = fmaxf(m, exch[gg][w][c]);
            run16[w] = m;
        }

        if (hg == 0) {  // wave 0 publishes full-column h-max
            float* hp = hpart + (size_t)TI * (TW * C) + c;
#pragma unroll
            for (int w = 0; w < TW; ++w) {
                float m = fmaxf(fmaxf(exch[0][w][c], exch[1][w][c]),
                                fmaxf(exch[2][w][c], exch[3][w][c]));
                hp[w * C] = m;
            }
        }
        {   // every wave publishes its 4 rows' w-max
            float* wp = wpart + (size_t)TI * (TH * C) + (hg * HH) * C + c;
#pragma unroll
            for (int hh = 0; hh < HH; ++hh) {
                float m = v[hh][0];
#pragma unroll
                for (int w = 1; w < TW; ++w) m = fmaxf(m, v[hh][w]);
                wp[hh * C] = m;
            }
        }
        __threadfence();                 // make partials agent-visible
        __syncthreads();                 // all waves' stores done
        if (tid == 0)
            __hip_atomic_store(&flags[TI], 1, __ATOMIC_RELEASE,
                               __HIP_MEMORY_SCOPE_AGENT);

        // ---- 3. decoupled lookback --------------------------------------
        for (int tp = t + 1; tp < NTH; ++tp) {           // tiles below
            const int TIp = (b * NTH + tp) * NTW + s;
            while (__hip_atomic_load(&flags[TIp], __ATOMIC_ACQUIRE,
                                     __HIP_MEMORY_SCOPE_AGENT) == 0)
                __builtin_amdgcn_s_sleep(8);
            const float* hp = hpart + (size_t)TIp * (TW * C) + c;
#pragma unroll
            for (int w = 0; w < TW; ++w)
                run16[w] = fmaxf(run16[w], hp[w * C]);
        }
        float wlook[HH];
#pragma unroll
        for (int hh = 0; hh < HH; ++hh) wlook[hh] = -FLT_MAX;
        for (int sp = s + 1; sp < NTW; ++sp) {           // tiles to the right
            const int TIp = (b * NTH + t) * NTW + sp;
            while (__hip_atomic_load(&flags[TIp], __ATOMIC_ACQUIRE,
                                     __HIP_MEMORY_SCOPE_AGENT) == 0)
                __builtin_amdgcn_s_sleep(8);
            const float* wp = wpart + (size_t)TIp * (TH * C) + (hg * HH) * C + c;
#pragma unroll
            for (int hh = 0; hh < HH; ++hh)
                wlook[hh] = fmaxf(wlook[hh], wp[hh * C]);
        }

        // ---- 4. output: rows descending, in-register suffixes -----------
        float* op = out + imgbase;
#pragma unroll
        for (int hh = HH - 1; hh >= 0; --hh) {
#pragma unroll
            for (int w = 0; w < TW; ++w)
                run16[w] = fmaxf(run16[w], v[hh][w]);    // inclusive h-suffix
            float ws = wlook[hh];
#pragma unroll
            for (int w = TW - 1; w >= 0; --w) {
                ws = fmaxf(ws, v[hh][w]);                // inclusive w-suffix
                __builtin_nontemporal_store(run16[w] + ws,
                                            &op[(size_t)hh * (W * C) + w * C]);
            }
        }
    }
}

// ---------------------------------------------------------------------------
// Fallback A (R2-proven, 155 us): 3-kernel tiled separable scans.
// ---------------------------------------------------------------------------
__global__ __launch_bounds__(256) void k_tilemax(const float* __restrict__ in,
                                                 float* __restrict__ hTile,
                                                 float* __restrict__ wTile)
{
    int blk = blockIdx.x;
    int wq = blk & 3;
    int t  = (blk >> 2) & (NTH - 1);
    int b  = blk >> 6;
    int tid = threadIdx.x;
    int c  = tid & 63;
    int wg = tid >> 6;
    int wbase = wq * 64 + wg * 16;
    int s = wbase / TW;

    float hrun[16];
#pragma unroll
    for (int j = 0; j < 16; ++j) hrun[j] = -FLT_MAX;

    int h0 = t * TH;
    for (int hh = 0; hh < TH; ++hh) {
        int h = h0 + hh;
        const float* row = in + ((size_t)(b * H + h) * W + wbase) * C + c;
        float wmax = -FLT_MAX;
#pragma unroll
        for (int j = 0; j < 16; ++j) {
            float v = row[j * C];
            hrun[j] = fmaxf(hrun[j], v);
            wmax = fmaxf(wmax, v);
        }
        wTile[((size_t)(b * H + h) * NTW + s) * C + c] = wmax;
    }
    float* hout = hTile + ((size_t)(b * NTH + t) * W + wbase) * C + c;
#pragma unroll
    for (int j = 0; j < 16; ++j) hout[j * C] = hrun[j];
}

__global__ __launch_bounds__(256) void k_sufscan2(float* __restrict__ hT,
                                                  float* __restrict__ wT)
{
    int idx = blockIdx.x * 256 + threadIdx.x;
    float* buf;
    int shift;
    if (idx < B * W * C) { buf = hT; shift = 14; }
    else                 { buf = wT; shift = 6; idx -= B * W * C; }
    int inner = 1 << shift;
    int o = idx >> shift;
    int i = idx & (inner - 1);
    float* p = buf + ((size_t)o * 16) * inner + i;
    float v[16];
#pragma unroll
    for (int tt = 0; tt < 16; ++tt) v[tt] = p[tt * inner];
    float run = -FLT_MAX;
#pragma unroll
    for (int tt = 15; tt >= 0; --tt) {
        float nv = v[tt];
        v[tt] = run;
        run = fmaxf(run, nv);
    }
#pragma unroll
    for (int tt = 0; tt < 16; ++tt) p[tt * inner] = v[tt];
}

__global__ __launch_bounds__(256) void k_final(const float* __restrict__ in,
                                               const float* __restrict__ hSuf,
                                               const float* __restrict__ wSuf,
                                               float* __restrict__ out)
{
    int blk = (gridDim.x - 1) - blockIdx.x;
    int wq = blk & 3;
    int t  = (blk >> 2) & (NTH - 1);
    int b  = blk >> 6;
    int tid = threadIdx.x;
    int c  = tid & 63;
    int wg = tid >> 6;
    int wbase = wq * 64 + wg * 16;
    int s = wbase / TW;

    float hrun[16];
    const float* hs = hSuf + ((size_t)(b * NTH + t) * W + wbase) * C + c;
#pragma unroll
    for (int j = 0; j < 16; ++j) hrun[j] = __builtin_nontemporal_load(&hs[j * C]);

    int h0 = t * TH;
    for (int hh = TH - 1; hh >= 0; --hh) {
        int h = h0 + hh;
        const float* row = in + ((size_t)(b * H + h) * W + wbase) * C + c;
        float v[16];
#pragma unroll
        for (int j = 0; j < 16; ++j) {
            v[j] = row[j * C];
            hrun[j] = fmaxf(hrun[j], v[j]);
        }
        float ws = __builtin_nontemporal_load(
            &wSuf[((size_t)(b * H + h) * NTW + s) * C + c]);
        float* orow = out + ((size_t)(b * H + h) * W + wbase) * C + c;
#pragma unroll
        for (int j = 15; j >= 0; --j) {
            ws = fmaxf(ws, v[j]);
            __builtin_nontemporal_store(hrun[j] + ws, &orow[j * C]);
        }
    }
}

// ---------------------------------------------------------------------------
// Fallback B (no workspace): serial scans.
// ---------------------------------------------------------------------------
__global__ __launch_bounds__(256) void k_wscan(const float* __restrict__ in,
                                               float* __restrict__ out)
{
    int idx = blockIdx.x * 256 + threadIdx.x;
    int c  = idx & 63;
    int bh = idx >> 6;
    const float* p = in + (size_t)bh * W * C + c;
    float* q = out + (size_t)bh * W * C + c;
    float run = -FLT_MAX;
    for (int w = W - 1; w >= 0; --w) {
        run = fmaxf(run, p[w * C]);
        q[w * C] = run;
    }
}

__global__ __launch_bounds__(256) void k_hscan_add(const float* __restrict__ in,
                                                   float* __restrict__ out)
{
    int idx = blockIdx.x * 256 + threadIdx.x;
    int wc = idx & (W * C - 1);
    int b  = idx >> 14;
    const float* p = in + (size_t)b * H * W * C + wc;
    float* q = out + (size_t)b * H * W * C + wc;
    float run = -FLT_MAX;
    for (int h = H - 1; h >= 0; --h) {
        run = fmaxf(run, p[(size_t)h * W * C]);
        q[(size_t)h * W * C] += run;
    }
}

extern "C" void kernel_launch(void* const* d_in, const int* in_sizes, int n_in,
                              void* d_out, int out_size, void* d_ws, size_t ws_size,
                              hipStream_t stream)
{
    const float* in = (const float*)d_in[0];
    float* out = (float*)d_out;

    // ws layout for persistent path:
    // [flags: NTILES ints][counter: 1 int][pad to 32KiB]
    // [hpart: NTILES*TW*C floats = 16 MiB][wpart: NTILES*TH*C floats = 16 MiB]
    const size_t partElems = (size_t)NTILES * TW * C;          // 4 Mi floats
    const size_t needNew = 32768 + 2 * partElems * sizeof(float);

    const size_t tileElems = (size_t)B * NTH * W * C;
    const size_t needOld = 2 * tileElems * sizeof(float);      // 32 MiB

    if (ws_size >= needNew) {
        int*   flags = (int*)d_ws;
        int*   counter = flags + NTILES;
        float* hpart = (float*)((char*)d_ws + 32768);
        float* wpart = hpart + partElems;

        k_init<<<16, 256, 0, stream>>>(flags);
        k_corner<<<GRID, 256, 0, stream>>>(in, out, hpart, wpart, flags, counter);
    } else if (ws_size >= needOld) {
        float* hTile = (float*)d_ws;
        float* wTile = hTile + tileElems;
        k_tilemax<<<B * NTH * (W / 64), 256, 0, stream>>>(in, hTile, wTile);
        k_sufscan2<<<2 * B * W * C / 256, 256, 0, stream>>>(hTile, wTile);
        k_final<<<B * NTH * (W / 64), 256, 0, stream>>>(in, hTile, wTile, out);
    } else {
        k_wscan<<<B * H * C / 256, 256, 0, stream>>>(in, out);
        k_hscan_add<<<B * W * C / 256, 256, 0, stream>>>(in, out);
    }
}

// Round 5
// 157.684 us; speedup vs baseline: 15.9851x; 15.9851x over previous
//
#include <hip/hip_runtime.h>
#include <float.h>

#define B 16
#define H 256
#define W 256
#define C 64
#define TH 16
#define NTH (H / TH)   // 16 h-tiles

// ---------------------------------------------------------------------------
// k_hpart: hTile[b][t][w][c] = max over the 16 rows of h-tile t.
// grid = B*NTH*4 = 1024 blocks, 256 threads.
// thread: c = tid&63 (lane=channel, 256B coalesced), wg = tid>>6;
// covers w = (blk&3)*64 + wg*16 + j, j in [0,16).
// Read 256 MiB, write 16 MiB. No w-partials (w handled in-block in k_fuse).
// ---------------------------------------------------------------------------
__global__ __launch_bounds__(256) void k_hpart(const float* __restrict__ in,
                                               float* __restrict__ hTile)
{
    int blk = blockIdx.x;
    int wq = blk & 3;
    int t  = (blk >> 2) & (NTH - 1);
    int b  = blk >> 6;
    int tid = threadIdx.x;
    int c  = tid & 63;
    int wg = tid >> 6;
    int wbase = wq * 64 + wg * 16;

    float hrun[16];
#pragma unroll
    for (int j = 0; j < 16; ++j) hrun[j] = -FLT_MAX;

    for (int hh = 0; hh < TH; ++hh) {
        const float* row = in + ((size_t)(b * H + t * TH + hh) * W + wbase) * C + c;
#pragma unroll
        for (int j = 0; j < 16; ++j)
            hrun[j] = fmaxf(hrun[j], row[j * C]);
    }
    float* hout = hTile + ((size_t)(b * NTH + t) * W + wbase) * C + c;
#pragma unroll
    for (int j = 0; j < 16; ++j) hout[j * C] = hrun[j];
}

// ---------------------------------------------------------------------------
// k_hsufscan: in-place EXCLUSIVE suffix-max over the 16 h-tiles.
// hTile layout [B][16][W*C]; one thread per (b, w*c) column.
// grid = B*W*C/256 = 1024 blocks. 32 MiB r/w, mostly L2/L3.
// ---------------------------------------------------------------------------
__global__ __launch_bounds__(256) void k_hsufscan(float* __restrict__ hT)
{
    int idx = blockIdx.x * 256 + threadIdx.x;
    int o = idx >> 14;                 // batch  (W*C = 2^14)
    int i = idx & (W * C - 1);
    float* p = hT + (size_t)o * NTH * (W * C) + i;
    float v[16];
#pragma unroll
    for (int tt = 0; tt < 16; ++tt) v[tt] = p[tt * (W * C)];
    float run = -FLT_MAX;
#pragma unroll
    for (int tt = 15; tt >= 0; --tt) {
        float nv = v[tt];
        v[tt] = run;                   // exclusive: max over tiles strictly below
        run = fmaxf(run, nv);
    }
#pragma unroll
    for (int tt = 0; tt < 16; ++tt) p[tt * (W * C)] = v[tt];
}

// ---------------------------------------------------------------------------
// k_fuse: final pass, whole w-extent per block -> w-suffix computed in-block.
// block = (b, t, c-half): grid = B*NTH*2 = 512 blocks, 512 threads.
// thread = (g = tid>>5 in [0,16), c32 = tid&31): owns w = g*16 + j, j in [0,16)
// at channel c = chalf*32 + c32. Per row (h descending within tile):
//   hrun[j] = max(hrun[j], v[j])        (seeded from exclusive hTile suffix)
//   in-thread w-suffix of v + LDS combine across the 16 g-groups
//   out = hrun + wsuf   (non-temporal stores)
// Read 256+16 MiB, write 256 MiB nt. ~44 VGPR -> high occupancy.
// ---------------------------------------------------------------------------
__global__ __launch_bounds__(512) void k_fuse(const float* __restrict__ in,
                                              const float* __restrict__ hSuf,
                                              float* __restrict__ out)
{
    __shared__ float exch[16][32];     // 2 KiB
    int blk = blockIdx.x;
    int ch = blk & 1;
    int t  = (blk >> 1) & (NTH - 1);
    int b  = blk >> 5;
    int tid = threadIdx.x;
    int c32 = tid & 31;
    int g   = tid >> 5;                // 0..15
    int c = ch * 32 + c32;
    int wbase = g * 16;

    float hrun[16];
    const float* hs = hSuf + ((size_t)(b * NTH + t) * W + wbase) * C + c;
#pragma unroll
    for (int j = 0; j < 16; ++j) hrun[j] = hs[j * C];

    for (int hh = TH - 1; hh >= 0; --hh) {
        const float* row = in + ((size_t)(b * H + t * TH + hh) * W + wbase) * C + c;
        float v[16];
#pragma unroll
        for (int j = 0; j < 16; ++j) v[j] = row[j * C];
#pragma unroll
        for (int j = 0; j < 16; ++j) hrun[j] = fmaxf(hrun[j], v[j]);
        // in-thread inclusive w-suffix (in place): v[j] = max(v[j..15])
#pragma unroll
        for (int j = 14; j >= 0; --j) v[j] = fmaxf(v[j], v[j + 1]);
        exch[g][c32] = v[0];
        __syncthreads();
        float seed = -FLT_MAX;
        for (int gg = g + 1; gg < 16; ++gg) seed = fmaxf(seed, exch[gg][c32]);
        __syncthreads();               // protect exch before next row's write
        float* orow = out + ((size_t)(b * H + t * TH + hh) * W + wbase) * C + c;
#pragma unroll
        for (int j = 0; j < 16; ++j)
            __builtin_nontemporal_store(hrun[j] + fmaxf(v[j], seed),
                                        &orow[j * C]);
    }
}

// ---------------------------------------------------------------------------
// Fallback (no workspace): two serial-scan kernels, fully coalesced.
// ---------------------------------------------------------------------------
__global__ __launch_bounds__(256) void k_wscan(const float* __restrict__ in,
                                               float* __restrict__ out)
{
    int idx = blockIdx.x * 256 + threadIdx.x;
    int c  = idx & 63;
    int bh = idx >> 6;
    const float* p = in + (size_t)bh * W * C + c;
    float* q = out + (size_t)bh * W * C + c;
    float run = -FLT_MAX;
    for (int w = W - 1; w >= 0; --w) {
        run = fmaxf(run, p[w * C]);
        q[w * C] = run;
    }
}

__global__ __launch_bounds__(256) void k_hscan_add(const float* __restrict__ in,
                                                   float* __restrict__ out)
{
    int idx = blockIdx.x * 256 + threadIdx.x;
    int wc = idx & (W * C - 1);
    int b  = idx >> 14;
    const float* p = in + (size_t)b * H * W * C + wc;
    float* q = out + (size_t)b * H * W * C + wc;
    float run = -FLT_MAX;
    for (int h = H - 1; h >= 0; --h) {
        run = fmaxf(run, p[(size_t)h * W * C]);
        q[(size_t)h * W * C] += run;
    }
}

extern "C" void kernel_launch(void* const* d_in, const int* in_sizes, int n_in,
                              void* d_out, int out_size, void* d_ws, size_t ws_size,
                              hipStream_t stream)
{
    const float* in = (const float*)d_in[0];
    float* out = (float*)d_out;

    const size_t tileElems = (size_t)B * NTH * W * C;      // 4 Mi floats = 16 MiB
    const size_t need = tileElems * sizeof(float);

    if (ws_size >= need) {
        float* hTile = (float*)d_ws;
        k_hpart<<<B * NTH * 4, 256, 0, stream>>>(in, hTile);
        k_hsufscan<<<B * W * C / 256, 256, 0, stream>>>(hTile);
        k_fuse<<<B * NTH * 2, 512, 0, stream>>>(in, hTile, out);
    } else {
        k_wscan<<<B * H * C / 256, 256, 0, stream>>>(in, out);
        k_hscan_add<<<B * W * C / 256, 256, 0, stream>>>(in, out);
    }
}

// Round 6
// 155.392 us; speedup vs baseline: 16.2209x; 1.0147x over previous
//
#include <hip/hip_runtime.h>
#include <float.h>

#define B 16
#define H 256
#define W 256
#define C 64
#define T8 8            // rows per h-tile
#define NT (H / T8)     // 32 h-tiles

typedef float f4 __attribute__((ext_vector_type(4)));

__device__ __forceinline__ f4 fmax4(f4 a, f4 b)
{
    f4 r;
    r.x = fmaxf(a.x, b.x);
    r.y = fmaxf(a.y, b.y);
    r.z = fmaxf(a.z, b.z);
    r.w = fmaxf(a.w, b.w);
    return r;
}

// ---------------------------------------------------------------------------
// k_colscan: fused pass-1 + tile scan. One thread per (w, c-quad); scans its
// whole column (256 rows) in 8-row chunks, t descending, writing the
// EXCLUSIVE 8-row-granular h-suffix:
//   hSuf[b][t][w][c] = max over rows h >= (t+1)*8 of in[b,h,w,c]
// grid = B*16 = 256 blocks x 256 threads (c4 = tid&15, wl = tid>>4).
// Wave = 16 c-quads x 4 w -> 1 KiB contiguous per load instruction.
// Traffic: 256 MiB read + 32 MiB write. Latency hidden by 8 independent
// dwordx4 loads in flight per thread (4 waves/CU only).
// ---------------------------------------------------------------------------
__global__ __launch_bounds__(256) void k_colscan(const float* __restrict__ in,
                                                 float* __restrict__ hSuf)
{
    int b   = blockIdx.x >> 4;
    int w16 = blockIdx.x & 15;
    int c4  = threadIdx.x & 15;
    int wl  = threadIdx.x >> 4;
    int w   = w16 * 16 + wl;

    const f4* ip = (const f4*)(in + ((size_t)b * H * W + w) * C) + c4;  // h stride W*C/4
    f4*       hp = (f4*)(hSuf + ((size_t)b * NT * W + w) * C) + c4;     // t stride W*C/4
    const size_t RS = (size_t)W * C / 4;   // 4096 f4

    f4 run = {-FLT_MAX, -FLT_MAX, -FLT_MAX, -FLT_MAX};
    for (int t = NT - 1; t >= 0; --t) {
        f4 l[T8];
#pragma unroll
        for (int hh = 0; hh < T8; ++hh)
            l[hh] = ip[(size_t)(t * T8 + hh) * RS];
        hp[(size_t)t * RS] = run;          // exclusive suffix for this tile
        f4 m = fmax4(fmax4(fmax4(l[0], l[1]), fmax4(l[2], l[3])),
                     fmax4(fmax4(l[4], l[5]), fmax4(l[6], l[7])));
        run = fmax4(run, m);
    }
}

// ---------------------------------------------------------------------------
// k_fuse: final pass over one 8-row x full-W x full-C tile per block.
// 512 threads: c4 = tid&15 (dwordx4 along c), g = tid>>4 in [0,32); group g
// owns w = g*8 + j, j<8. Per row (h descending):
//   hrun[j] = max(hrun[j], v[j])            (seeded from exclusive hSuf)
//   in-thread w-suffix over its 8 w + LDS combine across the 32 groups
//   out = hrun + wsuf                       (non-temporal dwordx4 stores)
// grid = B*NT = 512 blocks (2/CU, 16 waves/CU).
// ---------------------------------------------------------------------------
__global__ __launch_bounds__(512) void k_fuse(const float* __restrict__ in,
                                              const float* __restrict__ hSuf,
                                              float* __restrict__ out)
{
    __shared__ f4 exch[32][16];   // 8 KiB
    int b  = blockIdx.x >> 5;
    int t  = blockIdx.x & 31;
    int c4 = threadIdx.x & 15;
    int g  = threadIdx.x >> 4;    // 0..31
    int wb = g * 8;

    const f4* hs = (const f4*)(hSuf + ((size_t)(b * NT + t) * W + wb) * C) + c4;
    f4 hrun[8];
#pragma unroll
    for (int j = 0; j < 8; ++j)
        hrun[j] = __builtin_nontemporal_load(&hs[j * 16]);   // w stride = 16 f4

    for (int hh = T8 - 1; hh >= 0; --hh) {
        const size_t roff = ((size_t)(b * H + t * T8 + hh) * W + wb) * (C / 4) + c4;
        const f4* row = (const f4*)in + roff;
        f4 v[8];
#pragma unroll
        for (int j = 0; j < 8; ++j) v[j] = row[j * 16];
#pragma unroll
        for (int j = 0; j < 8; ++j) hrun[j] = fmax4(hrun[j], v[j]);
        // in-thread inclusive w-suffix over this group's 8 w
#pragma unroll
        for (int j = 6; j >= 0; --j) v[j] = fmax4(v[j], v[j + 1]);
        __syncthreads();                    // prev row's exch readers done
        exch[g][c4] = v[0];                 // group max (all its 8 w)
        __syncthreads();
        f4 seed = {-FLT_MAX, -FLT_MAX, -FLT_MAX, -FLT_MAX};
        for (int gg = g + 1; gg < 32; ++gg)
            seed = fmax4(seed, exch[gg][c4]);
        f4* orow = (f4*)out + roff;
#pragma unroll
        for (int j = 0; j < 8; ++j)
            __builtin_nontemporal_store(hrun[j] + fmax4(v[j], seed),
                                        &orow[j * 16]);
    }
}

// ---------------------------------------------------------------------------
// Fallback (no workspace): two serial-scan kernels, fully coalesced.
// ---------------------------------------------------------------------------
__global__ __launch_bounds__(256) void k_wscan(const float* __restrict__ in,
                                               float* __restrict__ out)
{
    int idx = blockIdx.x * 256 + threadIdx.x;
    int c  = idx & 63;
    int bh = idx >> 6;
    const float* p = in + (size_t)bh * W * C + c;
    float* q = out + (size_t)bh * W * C + c;
    float run = -FLT_MAX;
    for (int w = W - 1; w >= 0; --w) {
        run = fmaxf(run, p[w * C]);
        q[w * C] = run;
    }
}

__global__ __launch_bounds__(256) void k_hscan_add(const float* __restrict__ in,
                                                   float* __restrict__ out)
{
    int idx = blockIdx.x * 256 + threadIdx.x;
    int wc = idx & (W * C - 1);
    int b  = idx >> 14;
    const float* p = in + (size_t)b * H * W * C + wc;
    float* q = out + (size_t)b * H * W * C + wc;
    float run = -FLT_MAX;
    for (int h = H - 1; h >= 0; --h) {
        run = fmaxf(run, p[(size_t)h * W * C]);
        q[(size_t)h * W * C] += run;
    }
}

extern "C" void kernel_launch(void* const* d_in, const int* in_sizes, int n_in,
                              void* d_out, int out_size, void* d_ws, size_t ws_size,
                              hipStream_t stream)
{
    const float* in = (const float*)d_in[0];
    float* out = (float*)d_out;

    const size_t need = (size_t)B * NT * W * C * sizeof(float);   // 32 MiB

    if (ws_size >= need) {
        float* hSuf = (float*)d_ws;
        k_colscan<<<B * 16, 256, 0, stream>>>(in, hSuf);
        k_fuse<<<B * NT, 512, 0, stream>>>(in, hSuf, out);
    } else {
        k_wscan<<<B * H * C / 256, 256, 0, stream>>>(in, out);
        k_hscan_add<<<B * W * C / 256, 256, 0, stream>>>(in, out);
    }
}

// Round 7
// 147.224 us; speedup vs baseline: 17.1209x; 1.0555x over previous
//
#include <hip/hip_runtime.h>
#include <float.h>

#define B 16
#define H 256
#define W 256
#define C 64
#define T8 8            // rows per h-tile
#define NT (H / T8)     // 32 h-tiles

typedef float f4 __attribute__((ext_vector_type(4)));

__device__ __forceinline__ f4 fmax4(f4 a, f4 b)
{
    f4 r;
    r.x = fmaxf(a.x, b.x);
    r.y = fmaxf(a.y, b.y);
    r.z = fmaxf(a.z, b.z);
    r.w = fmaxf(a.w, b.w);
    return r;
}

__device__ __forceinline__ f4 shfl_down4(f4 a, int d)
{
    f4 r;
    r.x = __shfl_down(a.x, d, 64);
    r.y = __shfl_down(a.y, d, 64);
    r.z = __shfl_down(a.z, d, 64);
    r.w = __shfl_down(a.w, d, 64);
    return r;
}

// ---------------------------------------------------------------------------
// k_colscan: fused pass-1 + tile scan (unchanged from R6). One thread per
// (w, c-quad); scans its whole column (256 rows) in 8-row chunks, t
// descending, writing the EXCLUSIVE 8-row-granular h-suffix:
//   hSuf[b][t][w][c] = max over rows h >= (t+1)*8 of in[b,h,w,c]
// grid = B*16 = 256 blocks x 256 threads. 256 MiB read + 32 MiB write.
// ---------------------------------------------------------------------------
__global__ __launch_bounds__(256) void k_colscan(const float* __restrict__ in,
                                                 float* __restrict__ hSuf)
{
    int b   = blockIdx.x >> 4;
    int w16 = blockIdx.x & 15;
    int c4  = threadIdx.x & 15;
    int wl  = threadIdx.x >> 4;
    int w   = w16 * 16 + wl;

    const f4* ip = (const f4*)(in + ((size_t)b * H * W + w) * C) + c4;
    f4*       hp = (f4*)(hSuf + ((size_t)b * NT * W + w) * C) + c4;
    const size_t RS = (size_t)W * C / 4;   // 4096 f4

    f4 run = {-FLT_MAX, -FLT_MAX, -FLT_MAX, -FLT_MAX};
    for (int t = NT - 1; t >= 0; --t) {
        f4 l[T8];
#pragma unroll
        for (int hh = 0; hh < T8; ++hh)
            l[hh] = ip[(size_t)(t * T8 + hh) * RS];
        hp[(size_t)t * RS] = run;          // exclusive suffix for this tile
        f4 m = fmax4(fmax4(fmax4(l[0], l[1]), fmax4(l[2], l[3])),
                     fmax4(fmax4(l[4], l[5]), fmax4(l[6], l[7])));
        run = fmax4(run, m);
    }
}

// ---------------------------------------------------------------------------
// k_fuse: final pass over one 8-row x full-W x full-C tile per block.
// 512 threads: c4 = tid&15, g = tid>>4 in [0,32); group g owns w = g*8+j.
// Wave wv = tid>>6 holds local groups gl = (tid>>4)&3.
// Per row (h descending):
//   hrun[j] = max(hrun[j], v[j])          (seeded from exclusive hSuf)
//   in-thread w-suffix over the 8 owned w
//   in-WAVE suffix over 4 local groups via 2 shfl_down rounds (no LDS)
//   1 LDS write (wave leader) + barrier + <=7 cross-wave LDS reads
//   out = hrun + max(v, seed)             (non-temporal dwordx4 stores)
// Per-row LDS slot -> ONE barrier per row. grid = B*NT = 512 blocks.
// ---------------------------------------------------------------------------
__global__ __launch_bounds__(512) void k_fuse(const float* __restrict__ in,
                                              const float* __restrict__ hSuf,
                                              float* __restrict__ out)
{
    __shared__ f4 exch[T8][8][16];   // 16 KiB: [row][wave][c4]
    int b  = blockIdx.x >> 5;
    int t  = blockIdx.x & 31;
    int c4 = threadIdx.x & 15;
    int g  = threadIdx.x >> 4;       // 0..31
    int gl = g & 3;                  // local group within wave
    int wv = threadIdx.x >> 6;       // 0..7
    int wb = g * 8;

    const f4* hs = (const f4*)(hSuf + ((size_t)(b * NT + t) * W + wb) * C) + c4;
    f4 hrun[8];
#pragma unroll
    for (int j = 0; j < 8; ++j)
        hrun[j] = hs[j * 16];        // plain load: 32 MiB, expect L2/L3 hit

    for (int hh = T8 - 1; hh >= 0; --hh) {
        const size_t roff = ((size_t)(b * H + t * T8 + hh) * W + wb) * (C / 4) + c4;
        const f4* row = (const f4*)in + roff;
        f4 v[8];
#pragma unroll
        for (int j = 0; j < 8; ++j) v[j] = row[j * 16];
#pragma unroll
        for (int j = 0; j < 8; ++j) hrun[j] = fmax4(hrun[j], v[j]);
        // in-thread inclusive w-suffix over this group's 8 w
#pragma unroll
        for (int j = 6; j >= 0; --j) v[j] = fmax4(v[j], v[j + 1]);

        // in-wave inclusive suffix over the 4 local groups (lane stride 16)
        f4 s = v[0];                           // group total
        f4 tt = shfl_down4(s, 16);
        if (gl < 3) s = fmax4(s, tt);
        tt = shfl_down4(s, 32);
        if (gl < 2) s = fmax4(s, tt);
        // s = max over local groups gl..3; exclusive version:
        f4 e = shfl_down4(s, 16);
        if (gl == 3) e = (f4){-FLT_MAX, -FLT_MAX, -FLT_MAX, -FLT_MAX};

        if (gl == 0) exch[hh][wv][c4] = s;     // wave total (groups 4wv..4wv+3)
        __syncthreads();
        f4 seed = e;
        for (int wp = wv + 1; wp < 8; ++wp)
            seed = fmax4(seed, exch[hh][wp][c4]);

        f4* orow = (f4*)out + roff;
#pragma unroll
        for (int j = 0; j < 8; ++j)
            __builtin_nontemporal_store(hrun[j] + fmax4(v[j], seed),
                                        &orow[j * 16]);
    }
}

// ---------------------------------------------------------------------------
// Fallback (no workspace): two serial-scan kernels, fully coalesced.
// ---------------------------------------------------------------------------
__global__ __launch_bounds__(256) void k_wscan(const float* __restrict__ in,
                                               float* __restrict__ out)
{
    int idx = blockIdx.x * 256 + threadIdx.x;
    int c  = idx & 63;
    int bh = idx >> 6;
    const float* p = in + (size_t)bh * W * C + c;
    float* q = out + (size_t)bh * W * C + c;
    float run = -FLT_MAX;
    for (int w = W - 1; w >= 0; --w) {
        run = fmaxf(run, p[w * C]);
        q[w * C] = run;
    }
}

__global__ __launch_bounds__(256) void k_hscan_add(const float* __restrict__ in,
                                                   float* __restrict__ out)
{
    int idx = blockIdx.x * 256 + threadIdx.x;
    int wc = idx & (W * C - 1);
    int b  = idx >> 14;
    const float* p = in + (size_t)b * H * W * C + wc;
    float* q = out + (size_t)b * H * W * C + wc;
    float run = -FLT_MAX;
    for (int h = H - 1; h >= 0; --h) {
        run = fmaxf(run, p[(size_t)h * W * C]);
        q[(size_t)h * W * C] += run;
    }
}

extern "C" void kernel_launch(void* const* d_in, const int* in_sizes, int n_in,
                              void* d_out, int out_size, void* d_ws, size_t ws_size,
                              hipStream_t stream)
{
    const float* in = (const float*)d_in[0];
    float* out = (float*)d_out;

    const size_t need = (size_t)B * NT * W * C * sizeof(float);   // 32 MiB

    if (ws_size >= need) {
        float* hSuf = (float*)d_ws;
        k_colscan<<<B * 16, 256, 0, stream>>>(in, hSuf);
        k_fuse<<<B * NT, 512, 0, stream>>>(in, hSuf, out);
    } else {
        k_wscan<<<B * H * C / 256, 256, 0, stream>>>(in, out);
        k_hscan_add<<<B * W * C / 256, 256, 0, stream>>>(in, out);
    }
}